// Round 6
// baseline (204.956 us; speedup 1.0000x reference)
//
#include <hip/hip_runtime.h>
#include <stdint.h>

// graphConv: out[b] = (sum_k W_k S^k) @ X_b ; B=128, N=1024, D=64, K=8
//
// All-fp16 tree (fp32 MFMA accumulate), 32x32x16 MFMA (2x FLOP/instr and
// 2x FLOP per ds_read_b128 vs 16x16x32):
//   cvt: S (rm+cm), W1,W3,W5,W7 (rm) -> fp16
//   L1: S2 = S*S (rm+cm) ; U_j = W_{2j}(fp32 add) + W_{2j+1}*S  [5 jobs]
//   L2: S4 = S2*S2 (cm) ; V0 = U0 + U1*S2 ; V1 = U2 + U3*S2     [3 jobs]
//   L3: P = V1*S4, split-K=4 fp32 partials (non-atomic)
//   combine: A = V0 + sum P
//   apply: out[b] = A @ X_b  (128n x 64d x batch blocks; XCD=b%8 keeps the
//          XT slice on one XCD's L2, A L2-resident)
// LDS: BK=64, 128B rows, 16B chunks XOR-swizzled by row&7 (R2-verified
// conflict-free; 32-row fragment reads keep 8 distinct positions per 8-lane
// group), staged via global_load_lds width=16.

#define NN 1024
#define NBATCH 128
#define DDIM 64

typedef float floatx16 __attribute__((ext_vector_type(16)));
typedef _Float16 f16x8 __attribute__((ext_vector_type(8)));
typedef unsigned short u16;

__device__ __forceinline__ u16 f2h(float f) {
  union { _Float16 h; u16 u; } v; v.h = (_Float16)f; return v.u;
}
__device__ __forceinline__ float h2f(u16 u) {
  union { _Float16 h; u16 u; } v; v.u = u; return (float)v.h;
}

__device__ __forceinline__ void gll16(const void* g, void* l) {
  __builtin_amdgcn_global_load_lds(
      (const __attribute__((address_space(1))) void*)g,
      (__attribute__((address_space(3))) void*)l, 16, 0, 0);
}

// Stage ROWS x 64 u16 tile (row stride NN) into linear LDS, 16B chunks
// XOR-swizzled by row&7. Conflict-free on DMA write and ds_read_b128.
template <int ROWS>
__device__ __forceinline__ void stage64(const u16* __restrict__ g, u16* lds,
                                        int wave, int lane) {
  const int r = lane >> 3, c = lane & 7;
  const int sw = (c ^ r) * 8;
#pragma unroll
  for (int i = 0; i < ROWS / 32; ++i) {
    const int rb = wave * (ROWS / 4) + i * 8;
    gll16(g + (size_t)(rb + r) * NN + sw, lds + rb * 64);
  }
}

// Read one 8-f16 fragment for 32x32x16: row r (0..TILE), k-step ks (0..3),
// half = lane>>5. Physical chunk = (ks*2+half) ^ (r&7).
__device__ __forceinline__ f16x8 frag(const u16* lds, int r, int ks, int half) {
  return *(const f16x8*)&lds[r * 64 + (((ks * 2 + half) ^ (r & 7)) * 8)];
}

// ---------------- convert fp32 -> fp16, rm (+ optional cm) -----------------
struct CvtJob { const float* src; u16* rm; u16* cm; };
struct CvtJobs { CvtJob j[5]; };

__global__ __launch_bounds__(256) void cvt_kernel(CvtJobs jobs) {
  CvtJob jb = jobs.j[blockIdx.z];
  int idx4 = blockIdx.x * 256 + threadIdx.x;
  int e = idx4 * 4;
  int row = e >> 10, col = e & (NN - 1);
  float4 f = ((const float4*)jb.src)[idx4];
  u16 h[4] = { f2h(f.x), f2h(f.y), f2h(f.z), f2h(f.w) };
  uint2 p;
  p.x = (uint32_t)h[0] | ((uint32_t)h[1] << 16);
  p.y = (uint32_t)h[2] | ((uint32_t)h[3] << 16);
  *(uint2*)&jb.rm[e] = p;
  if (jb.cm) {
#pragma unroll
    for (int i = 0; i < 4; ++i) jb.cm[(size_t)(col + i) * NN + row] = h[i];
  }
}

// ---------------- transpose X [B,K,D] fp32 -> XT [B*D, K] fp16 -------------
__global__ __launch_bounds__(256) void transpose_x(const float* __restrict__ X,
                                                   u16* __restrict__ XT) {
  __shared__ u16 T[64][72];
  const int k0 = blockIdx.x * 64;
  const int b = blockIdx.y;
  const int t = threadIdx.x;
#pragma unroll
  for (int it = 0; it < 4; ++it) {
    int kr = (t >> 4) + it * 16;
    int d4 = (t & 15) * 4;
    float4 f = *(const float4*)&X[((size_t)b * NN + k0 + kr) * DDIM + d4];
    T[d4 + 0][kr] = f2h(f.x);
    T[d4 + 1][kr] = f2h(f.y);
    T[d4 + 2][kr] = f2h(f.z);
    T[d4 + 3][kr] = f2h(f.w);
  }
  __syncthreads();
#pragma unroll
  for (int it = 0; it < 2; ++it) {
    int d = (t >> 3) + it * 32;
    int kc = (t & 7) * 8;
    *(uint4*)&XT[((size_t)b * DDIM + d) * NN + k0 + kc] = *(uint4*)&T[d][kc];
  }
}

// ---------------- fp16 GEMM (32x32x16): out = [add +] A*B ------------------
struct GemmJob {
  const u16* A;        // fp16 row-major MxK
  const u16* B;        // fp16 col-major: (k,n) at [n*NN+k]
  const float* addF;   // optional fp32 additive (row-major)
  const u16* addH;     // optional fp16 additive (row-major)
  u16* outRm;          // optional fp16 row-major out
  u16* outCm;          // optional fp16 col-major out
  float* outP;         // split-K fp32 partials (KSPLIT>1 path)
};
struct GemmJobs { GemmJob j[5]; };

template <int BM, int BN, int KSPLIT>
__global__ __launch_bounds__(256) void gemm_f16(GemmJobs jobs) {
  const GemmJob jb = jobs.j[blockIdx.z / KSPLIT];
  const int chunk = blockIdx.z % KSPLIT;
  __shared__ u16 As[BM * 64], Bs[BN * 64];
  const int t = threadIdx.x, wave = t >> 6, lane = t & 63;
  const int wm = wave >> 1, wn = wave & 1;
  const int l31 = lane & 31, half = lane >> 5;
  const int bm = blockIdx.x * BM, bn = blockIdx.y * BN;
  constexpr int MI = BM / 64, NI = BN / 64, KTPB = 16 / KSPLIT;
  floatx16 acc[MI][NI] = {};

  for (int kk = 0; kk < KTPB; ++kk) {
    const int kt = chunk * KTPB + kk;
    __syncthreads();
    stage64<BM>(jb.A + (size_t)bm * NN + kt * 64, As, wave, lane);
    stage64<BN>(jb.B + (size_t)bn * NN + kt * 64, Bs, wave, lane);
    __syncthreads();
#pragma unroll
    for (int ks = 0; ks < 4; ++ks) {
      f16x8 bf[NI];
#pragma unroll
      for (int ni = 0; ni < NI; ++ni)
        bf[ni] = frag(Bs, wn * (BN / 2) + ni * 32 + l31, ks, half);
#pragma unroll
      for (int mi = 0; mi < MI; ++mi) {
        f16x8 a = frag(As, wm * (BM / 2) + mi * 32 + l31, ks, half);
#pragma unroll
        for (int ni = 0; ni < NI; ++ni)
          acc[mi][ni] = __builtin_amdgcn_mfma_f32_32x32x16_f16(a, bf[ni], acc[mi][ni], 0, 0, 0);
      }
    }
  }

#pragma unroll
  for (int mi = 0; mi < MI; ++mi)
#pragma unroll
    for (int ni = 0; ni < NI; ++ni)
#pragma unroll
      for (int r = 0; r < 16; ++r) {
        int row = bm + wm * (BM / 2) + mi * 32 + (r & 3) + 8 * (r >> 2) + 4 * half;
        int col = bn + wn * (BN / 2) + ni * 32 + l31;
        size_t rm = (size_t)row * NN + col;
        float v = acc[mi][ni][r];
        if (KSPLIT > 1) {
          jb.outP[(size_t)chunk * NN * NN + rm] = v;
        } else {
          if (jb.addF) v += jb.addF[rm];
          if (jb.addH) v += h2f(jb.addH[rm]);
          u16 h = f2h(v);
          if (jb.outRm) jb.outRm[rm] = h;
          if (jb.outCm) jb.outCm[(size_t)col * NN + row] = h;
        }
      }
}

// ---------------- combine: A = V0 + sum_z P --------------------------------
__global__ __launch_bounds__(256) void combine_A(const float* __restrict__ parts,
                                                 const u16* __restrict__ v0,
                                                 u16* __restrict__ A) {
  int e = (blockIdx.x * 256 + threadIdx.x) * 4;
  float4 s = *(const float4*)&parts[e];
#pragma unroll
  for (int z = 1; z < 4; ++z) {
    float4 p = *(const float4*)&parts[(size_t)z * NN * NN + e];
    s.x += p.x; s.y += p.y; s.z += p.z; s.w += p.w;
  }
  uint2 h = *(const uint2*)&v0[e];
  uint2 o;
  o.x = (uint32_t)f2h(s.x + h2f((u16)h.x)) |
        ((uint32_t)f2h(s.y + h2f((u16)(h.x >> 16))) << 16);
  o.y = (uint32_t)f2h(s.z + h2f((u16)h.y)) |
        ((uint32_t)f2h(s.w + h2f((u16)(h.y >> 16))) << 16);
  *(uint2*)&A[e] = o;
}

// ---------------- apply: out[b][n][d] = A @ X_b (32x32x16) -----------------
// Block = 128 n-rows x 64 d x one b; wave w owns rows w*32..w*32+31.
// grid(x=b, y=ntile): XCD = b%8 -> XT slice stays in one XCD's L2.
__global__ __launch_bounds__(256) void apply_gemm(const u16* __restrict__ A,
                                                  const u16* __restrict__ XT,
                                                  float* __restrict__ out) {
  __shared__ u16 As[8192], Xs[4096];  // 16 KB + 8 KB
  const int t = threadIdx.x, wave = t >> 6, lane = t & 63;
  const int l31 = lane & 31, half = lane >> 5;
  const int b = blockIdx.x, bm = blockIdx.y * 128;
  floatx16 acc[2] = {};

  for (int kt = 0; kt < 16; ++kt) {
    __syncthreads();
    stage64<128>(A + (size_t)bm * NN + kt * 64, As, wave, lane);
    stage64<64>(XT + (size_t)b * DDIM * NN + kt * 64, Xs, wave, lane);
    __syncthreads();
#pragma unroll
    for (int ks = 0; ks < 4; ++ks) {
      f16x8 a = frag(As, wave * 32 + l31, ks, half);
#pragma unroll
      for (int ni = 0; ni < 2; ++ni) {
        f16x8 x = frag(Xs, ni * 32 + l31, ks, half);
        acc[ni] = __builtin_amdgcn_mfma_f32_32x32x16_f16(a, x, acc[ni], 0, 0, 0);
      }
    }
  }

#pragma unroll
  for (int ni = 0; ni < 2; ++ni)
#pragma unroll
    for (int r = 0; r < 16; ++r) {
      int row = bm + wave * 32 + (r & 3) + 8 * (r >> 2) + 4 * half;
      int d = ni * 32 + l31;
      out[((size_t)b * NN + row) * DDIM + d] = acc[ni][r];
    }
}

extern "C" void kernel_launch(void* const* d_in, const int* in_sizes, int n_in,
                              void* d_out, int out_size, void* d_ws, size_t ws_size,
                              hipStream_t stream) {
  const float* nodes  = (const float*)d_in[0];  // [128,1024,64]
  const float* weight = (const float*)d_in[1];  // [8,1024,1024]
  const float* gs     = (const float*)d_in[2];  // [1024,1024]
  float* out = (float*)d_out;
  u16* ws = (u16*)d_ws;
  const size_t MB = (size_t)NN * NN;
  auto buf = [&](int i) -> u16* { return ws + (size_t)i * MB; };
  // 2MB fp16 slots: 0 S rm | 1 S cm | 2..5 W1,3,5,7 rm | 6 S2 rm | 7 S2 cm
  // 8..11 U0..U3 | 12 S4 cm | 13 V0 | 14 V1 | 15 A | 16..23 XT (16 MB)
  // 24..31 L3 fp32 partials (16 MB). Total 64 MB.

  CvtJobs cv{};
  cv.j[0] = { gs,              buf(0), buf(1) };
  cv.j[1] = { weight + 1 * MB, buf(2), nullptr };
  cv.j[2] = { weight + 3 * MB, buf(3), nullptr };
  cv.j[3] = { weight + 5 * MB, buf(4), nullptr };
  cv.j[4] = { weight + 7 * MB, buf(5), nullptr };
  cvt_kernel<<<dim3(NN * NN / 1024, 1, 5), 256, 0, stream>>>(cv);

  // L1: S2 = S*S ; U_j = W_{2j} + W_{2j+1}*S
  GemmJobs g1{};
  g1.j[0] = { buf(0), buf(1), nullptr,         nullptr, buf(6),  buf(7),  nullptr };
  g1.j[1] = { buf(2), buf(1), weight + 0 * MB, nullptr, buf(8),  nullptr, nullptr };
  g1.j[2] = { buf(3), buf(1), weight + 2 * MB, nullptr, buf(9),  nullptr, nullptr };
  g1.j[3] = { buf(4), buf(1), weight + 4 * MB, nullptr, buf(10), nullptr, nullptr };
  g1.j[4] = { buf(5), buf(1), weight + 6 * MB, nullptr, buf(11), nullptr, nullptr };
  gemm_f16<64, 128, 1><<<dim3(16, 8, 5), 256, 0, stream>>>(g1);

  u16* XT = buf(16);
  transpose_x<<<dim3(16, NBATCH), 256, 0, stream>>>(nodes, XT);

  // L2: S4 = S2*S2 (cm) ; V0 = U0 + U1*S2 ; V1 = U2 + U3*S2
  GemmJobs g2{};
  g2.j[0] = { buf(6),  buf(7), nullptr, nullptr, nullptr, buf(12), nullptr };
  g2.j[1] = { buf(9),  buf(7), nullptr, buf(8),  buf(13), nullptr, nullptr };
  g2.j[2] = { buf(11), buf(7), nullptr, buf(10), buf(14), nullptr, nullptr };
  gemm_f16<64, 64, 1><<<dim3(16, 16, 3), 256, 0, stream>>>(g2);

  // L3: P = V1*S4, split-K=4 non-atomic partials
  float* parts = (float*)buf(24);
  GemmJobs g3{};
  g3.j[0] = { buf(14), buf(12), nullptr, nullptr, nullptr, nullptr, parts };
  gemm_f16<64, 64, 4><<<dim3(16, 16, 4), 256, 0, stream>>>(g3);

  // A = V0 + sum P
  combine_A<<<dim3(NN * NN / 1024), 256, 0, stream>>>(parts, buf(13), buf(15));

  apply_gemm<<<dim3(NBATCH, 8), 256, 0, stream>>>(buf(15), XT, out);
}